// Round 1
// baseline (1142.288 us; speedup 1.0000x reference)
//
#include <hip/hip_runtime.h>
#include <hip/hip_bf16.h>

typedef __attribute__((ext_vector_type(8))) short s16x8;
typedef __attribute__((ext_vector_type(4))) float f32x4;

#define MFMA_B16(a, b, c) __builtin_amdgcn_mfma_f32_16x16x32_bf16((a), (b), (c), 0, 0, 0)

__device__ __forceinline__ short f2bf(float f) {
    __hip_bfloat16 h = __float2bfloat16(f);
    return __builtin_bit_cast(short, h);
}
__device__ __forceinline__ float bfbits2f(unsigned int lo16) {
    return __uint_as_float(lo16 << 16);
}
__device__ __forceinline__ float sigmoid_f(float x) {
    return __fdividef(1.0f, 1.0f + exp2f(-1.4426950408889634f * x));
}
__device__ __forceinline__ float tanh_f(float x) {
    return 1.0f - 2.0f * __fdividef(1.0f, 1.0f + exp2f(2.8853900817779268f * x));
}

// Ensemble LSTM: one WG per (series, batch-half). 8 waves, 512 threads.
// Wave w handles gate tiles {w, w+8, w+16, w+24} = (i,f,g,o) for hidden cols w*16..w*16+15.
// W_hh/W_ih B-fragments are loop-invariant -> held in VGPRs (80/wave).
// LDS: double-buffered h A-fragment buffer, fragment-linear (2 x 4KB).
__global__ __launch_bounds__(512, 2)
void clstm_kernel(const float* __restrict__ X,
                  const float* __restrict__ W_ih,
                  const float* __restrict__ W_hh,
                  const float* __restrict__ b_ih,
                  const float* __restrict__ b_hh,
                  const float* __restrict__ W_out,
                  const float* __restrict__ b_out,
                  float* __restrict__ out)
{
    constexpr int B = 32, T = 512, N = 32, H = 128, G = 512;  // G = 4H
    constexpr int HT_OFF = B * T * N;
    constexpr int CT_OFF = HT_OFF + N * B * H;

    __shared__ __align__(16) unsigned char smem[8192];

    const int tid  = threadIdx.x;
    const int w    = tid >> 6;   // wave 0..7
    const int L    = tid & 63;
    const int col  = L & 15;
    const int quad = L >> 4;
    const int n    = blockIdx.x >> 1;  // series
    const int bg   = blockIdx.x & 1;   // batch half

    // ---- loop-invariant weight fragments (fp32 -> bf16, one time) ----
    // B-frag layout (16x16x32): lane holds gate col g = tile*16 + (L&15),
    // k = kt*32 + quad*8 + jj  (jj = 0..7)
    s16x8 Bh[4][4];  // [gate tt][kt]  k = hidden 0..127
    s16x8 Bx[4];     // [gate tt]      k = input p 0..31
    float bias4[4];
#pragma unroll
    for (int tt = 0; tt < 4; ++tt) {
        const int g = (w + 8 * tt) * 16 + col;
        const float* whr = W_hh + ((size_t)n * G + g) * H + quad * 8;
#pragma unroll
        for (int kt = 0; kt < 4; ++kt) {
            const float* p = whr + kt * 32;
#pragma unroll
            for (int jj = 0; jj < 8; ++jj) Bh[tt][kt][jj] = f2bf(p[jj]);
        }
        const float* wir = W_ih + ((size_t)n * G + g) * N + quad * 8;
#pragma unroll
        for (int jj = 0; jj < 8; ++jj) Bx[tt][jj] = f2bf(wir[jj]);
        bias4[tt] = b_ih[n * G + g] + b_hh[n * G + g];
    }

    // ---- h writer offset: value h[b][j], b = quad*4+r, j = w*16+col ----
    // frag-linear addr: (j>>5)*1024 + ((b | (((j>>3)&3)<<4)) * 16) + (j&7)*2
    int wboff0;
    {
        const int j  = w * 16 + col;
        const int hi = (j >> 3) & 3;
        wboff0 = (j >> 5) * 1024 + (((hi << 4) | (quad * 4)) * 16) + (j & 7) * 2;
    }

    // ---- pred head constants: wave w covers batches {2w, 2w+1} ----
    const int bpred = 2 * w + (L >> 5);       // local batch 0..15
    const int cidx  = L & 31;                 // j-quad selector
    const int j0    = cidx * 4;
    const int pred_lds = (j0 >> 5) * 1024 + (((((j0 >> 3) & 3) << 4) | bpred) * 16) + (j0 & 7) * 2;
    const float4 wout = *(const float4*)(W_out + n * H + j0);
    const float  bo   = b_out[n];
    float* predp = out + ((size_t)(bg * 16 + bpred) * T) * N + n;

    // ---- x loader: b = bg*16 + col, p = quad*8 + jj ----
    const float* xptr = X + ((size_t)(bg * 16 + col) * T) * N + quad * 8;

    // zero h buffer 0 (h_{-1} = 0)
    ((float2*)smem)[tid] = make_float2(0.0f, 0.0f);

    float cst[4]   = {0.f, 0.f, 0.f, 0.f};
    float hlast[4] = {0.f, 0.f, 0.f, 0.f};

    float4 xlo0, xhi0, xlo1, xhi1;
    xlo0 = *(const float4*)(xptr);
    xhi0 = *(const float4*)(xptr + 4);

    __syncthreads();

#define HALF_STEP(P, TCUR, XLO_C, XHI_C, XLO_N, XHI_N)                              \
    {                                                                               \
        const int tnext = ((TCUR) + 1 < T) ? (TCUR) + 1 : T - 1;                    \
        XLO_N = *(const float4*)(xptr + (size_t)tnext * N);                         \
        XHI_N = *(const float4*)(xptr + (size_t)tnext * N + 4);                     \
        s16x8 xf;                                                                   \
        xf[0] = f2bf(XLO_C.x); xf[1] = f2bf(XLO_C.y);                               \
        xf[2] = f2bf(XLO_C.z); xf[3] = f2bf(XLO_C.w);                               \
        xf[4] = f2bf(XHI_C.x); xf[5] = f2bf(XHI_C.y);                               \
        xf[6] = f2bf(XHI_C.z); xf[7] = f2bf(XHI_C.w);                               \
        const unsigned char* rb = smem + (P) * 4096;                                \
        s16x8 Af[4];                                                                \
        _Pragma("unroll")                                                           \
        for (int kt = 0; kt < 4; ++kt)                                              \
            Af[kt] = *(const s16x8*)(rb + kt * 1024 + L * 16);                      \
        f32x4 acc[4];                                                               \
        _Pragma("unroll")                                                           \
        for (int tt = 0; tt < 4; ++tt)                                              \
            acc[tt] = (f32x4){bias4[tt], bias4[tt], bias4[tt], bias4[tt]};          \
        _Pragma("unroll")                                                           \
        for (int kt = 0; kt < 4; ++kt) {                                            \
            _Pragma("unroll")                                                       \
            for (int tt = 0; tt < 4; ++tt)                                          \
                acc[tt] = MFMA_B16(Af[kt], Bh[tt][kt], acc[tt]);                    \
        }                                                                           \
        _Pragma("unroll")                                                           \
        for (int tt = 0; tt < 4; ++tt)                                              \
            acc[tt] = MFMA_B16(xf, Bx[tt], acc[tt]);                                \
        unsigned char* wb = smem + ((P) ^ 1) * 4096;                                \
        _Pragma("unroll")                                                           \
        for (int r = 0; r < 4; ++r) {                                               \
            const float iv = acc[0][r], fv = acc[1][r];                             \
            const float gv = acc[2][r], ov = acc[3][r];                             \
            const float si = sigmoid_f(iv);                                         \
            const float sf = sigmoid_f(fv);                                         \
            const float tg = tanh_f(gv);                                            \
            const float so = sigmoid_f(ov);                                         \
            const float cc = sf * cst[r] + si * tg;                                 \
            cst[r] = cc;                                                            \
            const float hv = so * tanh_f(cc);                                       \
            hlast[r] = hv;                                                          \
            *(short*)(wb + wboff0 + r * 16) = f2bf(hv);                             \
        }                                                                           \
        __syncthreads();                                                            \
        const unsigned int* pb =                                                    \
            (const unsigned int*)(smem + ((P) ^ 1) * 4096 + pred_lds);              \
        const unsigned int h01 = pb[0], h23 = pb[1];                                \
        float part = bfbits2f(h01 & 0xffffu) * wout.x                               \
                   + bfbits2f(h01 >> 16)     * wout.y                               \
                   + bfbits2f(h23 & 0xffffu) * wout.z                               \
                   + bfbits2f(h23 >> 16)     * wout.w;                              \
        _Pragma("unroll")                                                           \
        for (int d = 16; d >= 1; d >>= 1) part += __shfl_xor(part, d, 64);          \
        if ((L & 31) == 0) predp[(size_t)(TCUR) * N] = part + bo;                   \
    }

#pragma unroll 1
    for (int t2 = 0; t2 < T; t2 += 2) {
        HALF_STEP(0, t2,     xlo0, xhi0, xlo1, xhi1)
        HALF_STEP(1, t2 + 1, xlo1, xhi1, xlo0, xhi0)
    }
#undef HALF_STEP

    // final hT, cT (fp32 from registers)
#pragma unroll
    for (int r = 0; r < 4; ++r) {
        const int bglob = bg * 16 + quad * 4 + r;
        const int j = w * 16 + col;
        out[HT_OFF + ((size_t)n * B + bglob) * H + j] = hlast[r];
        out[CT_OFF + ((size_t)n * B + bglob) * H + j] = cst[r];
    }
}

extern "C" void kernel_launch(void* const* d_in, const int* in_sizes, int n_in,
                              void* d_out, int out_size, void* d_ws, size_t ws_size,
                              hipStream_t stream) {
    const float* X     = (const float*)d_in[0];
    const float* W_ih  = (const float*)d_in[1];
    const float* W_hh  = (const float*)d_in[2];
    const float* b_ih  = (const float*)d_in[3];
    const float* b_hh  = (const float*)d_in[4];
    const float* W_out = (const float*)d_in[5];
    const float* b_out = (const float*)d_in[6];
    float* out = (float*)d_out;

    clstm_kernel<<<dim3(64), dim3(512), 0, stream>>>(
        X, W_ih, W_hh, b_ih, b_hh, W_out, b_out, out);
}

// Round 2
// 1062.502 us; speedup vs baseline: 1.0751x; 1.0751x over previous
//
#include <hip/hip_runtime.h>
#include <hip/hip_bf16.h>

typedef __attribute__((ext_vector_type(8))) short s16x8;
typedef __attribute__((ext_vector_type(4))) float f32x4;

#define MFMA_B16(a, b, c) __builtin_amdgcn_mfma_f32_16x16x32_bf16((a), (b), (c), 0, 0, 0)

__device__ __forceinline__ short f2bf(float f) {
    __hip_bfloat16 h = __float2bfloat16(f);
    return __builtin_bit_cast(short, h);
}
__device__ __forceinline__ float sigmoid_f(float x) {
    return __fdividef(1.0f, 1.0f + exp2f(-1.4426950408889634f * x));
}
__device__ __forceinline__ float tanh_f(float x) {
    return 1.0f - 2.0f * __fdividef(1.0f, 1.0f + exp2f(2.8853900817779268f * x));
}

// Ensemble LSTM: one WG per (series, batch-half). 8 waves, 512 threads.
// Wave w handles gate tiles {w, w+8, w+16, w+24} = (i,f,g,o) for hidden cols w*16..w*16+15.
// W_hh/W_ih B-fragments are loop-invariant -> held in VGPRs.
// pred head: h_t . W_out folded into one extra MFMA tile on wave 0 at step t+1
// (A-frags ARE h_t there) -- no shuffle reduction, no extra LDS reads.
// LDS: double-buffered h A-fragment buffer, fragment-linear (2 x 4KB).
__global__ __launch_bounds__(512, 2)
void clstm_kernel(const float* __restrict__ X,
                  const float* __restrict__ W_ih,
                  const float* __restrict__ W_hh,
                  const float* __restrict__ b_ih,
                  const float* __restrict__ b_hh,
                  const float* __restrict__ W_out,
                  const float* __restrict__ b_out,
                  float* __restrict__ out)
{
    constexpr int B = 32, T = 512, N = 32, H = 128, G = 512;  // G = 4H
    constexpr int HT_OFF = B * T * N;
    constexpr int CT_OFF = HT_OFF + N * B * H;

    __shared__ __align__(16) unsigned char smem[8192];

    const int tid  = threadIdx.x;
    const int w    = tid >> 6;   // wave 0..7
    const int L    = tid & 63;
    const int col  = L & 15;
    const int quad = L >> 4;
    const int n    = blockIdx.x >> 1;  // series
    const int bg   = blockIdx.x & 1;   // batch half

    // ---- loop-invariant weight fragments (fp32 -> bf16, one time) ----
    // B-frag layout (16x16x32): lane holds gate col g = tile*16 + (L&15),
    // k = kt*32 + quad*8 + jj  (jj = 0..7)
    s16x8 Bh[4][4];  // [gate tt][kt]  k = hidden 0..127
    s16x8 Bx[4];     // [gate tt]      k = input p 0..31
    float bias4[4];
#pragma unroll
    for (int tt = 0; tt < 4; ++tt) {
        const int g = (w + 8 * tt) * 16 + col;
        const float* whr = W_hh + ((size_t)n * G + g) * H + quad * 8;
#pragma unroll
        for (int kt = 0; kt < 4; ++kt) {
            const float* p = whr + kt * 32;
#pragma unroll
            for (int jj = 0; jj < 8; ++jj) Bh[tt][kt][jj] = f2bf(p[jj]);
        }
        const float* wir = W_ih + ((size_t)n * G + g) * N + quad * 8;
#pragma unroll
        for (int jj = 0; jj < 8; ++jj) Bx[tt][jj] = f2bf(wir[jj]);
        bias4[tt] = b_ih[n * G + g] + b_hh[n * G + g];
    }

    // ---- pred tile (wave 0 only): B col 0 = W_out, cols 1..15 = 0 ----
    s16x8 Bp[4];
    float bo = 0.0f;
    if (w == 0) {
        bo = b_out[n];
#pragma unroll
        for (int kt = 0; kt < 4; ++kt) {
            const float* wp = W_out + n * H + kt * 32 + quad * 8;
#pragma unroll
            for (int jj = 0; jj < 8; ++jj)
                Bp[kt][jj] = (col == 0) ? f2bf(wp[jj]) : (short)0;
        }
    }

    // ---- h writer offset: value h[b][j], b = quad*4+r, j = w*16+col ----
    // frag-linear addr: (j>>5)*1024 + ((b | (((j>>3)&3)<<4)) * 16) + (j&7)*2
    int wboff0;
    {
        const int j  = w * 16 + col;
        const int hi = (j >> 3) & 3;
        wboff0 = (j >> 5) * 1024 + (((hi << 4) | (quad * 4)) * 16) + (j & 7) * 2;
    }

    // ---- x loader: b = bg*16 + col, p = quad*8 + jj ----
    const float* xptr = X + ((size_t)(bg * 16 + col) * T) * N + quad * 8;

    // zero h buffer 0 (h_{-1} = 0)
    ((float2*)smem)[tid] = make_float2(0.0f, 0.0f);

    float cst[4]   = {0.f, 0.f, 0.f, 0.f};
    float hlast[4] = {0.f, 0.f, 0.f, 0.f};

    float4 xlo0, xhi0, xlo1, xhi1;
    xlo0 = *(const float4*)(xptr);
    xhi0 = *(const float4*)(xptr + 4);

    __syncthreads();

#define HALF_STEP(P, TCUR, XLO_C, XHI_C, XLO_N, XHI_N)                              \
    {                                                                               \
        const unsigned char* rb = smem + (P) * 4096;                                \
        s16x8 Af[4];                                                                \
        _Pragma("unroll")                                                           \
        for (int kt = 0; kt < 4; ++kt)                                              \
            Af[kt] = *(const s16x8*)(rb + kt * 1024 + L * 16);                      \
        const int tnext = ((TCUR) + 1 < T) ? (TCUR) + 1 : T - 1;                    \
        XLO_N = *(const float4*)(xptr + (size_t)tnext * N);                         \
        XHI_N = *(const float4*)(xptr + (size_t)tnext * N + 4);                     \
        s16x8 xf;                                                                   \
        xf[0] = f2bf(XLO_C.x); xf[1] = f2bf(XLO_C.y);                               \
        xf[2] = f2bf(XLO_C.z); xf[3] = f2bf(XLO_C.w);                               \
        xf[4] = f2bf(XHI_C.x); xf[5] = f2bf(XHI_C.y);                               \
        xf[6] = f2bf(XHI_C.z); xf[7] = f2bf(XHI_C.w);                               \
        f32x4 acc[4];                                                               \
        _Pragma("unroll")                                                           \
        for (int tt = 0; tt < 4; ++tt)                                              \
            acc[tt] = (f32x4){bias4[tt], bias4[tt], bias4[tt], bias4[tt]};          \
        _Pragma("unroll")                                                           \
        for (int kt = 0; kt < 4; ++kt) {                                            \
            _Pragma("unroll")                                                       \
            for (int tt = 0; tt < 4; ++tt)                                          \
                acc[tt] = MFMA_B16(Af[kt], Bh[tt][kt], acc[tt]);                    \
        }                                                                           \
        _Pragma("unroll")                                                           \
        for (int tt = 0; tt < 4; ++tt)                                              \
            acc[tt] = MFMA_B16(xf, Bx[tt], acc[tt]);                                \
        if (w == 0) {                                                               \
            f32x4 pacc = (f32x4){bo, bo, bo, bo};                                   \
            _Pragma("unroll")                                                       \
            for (int kt = 0; kt < 4; ++kt)                                          \
                pacc = MFMA_B16(Af[kt], Bp[kt], pacc);                              \
            if ((TCUR) > 0 && col == 0) {                                           \
                float* pp = out +                                                   \
                    ((size_t)(bg * 16 + quad * 4) * T + (TCUR) - 1) * N + n;        \
                _Pragma("unroll")                                                   \
                for (int r = 0; r < 4; ++r)                                         \
                    pp[(size_t)r * T * N] = pacc[r];                                \
            }                                                                       \
        }                                                                           \
        unsigned char* wb = smem + ((P) ^ 1) * 4096;                                \
        _Pragma("unroll")                                                           \
        for (int r = 0; r < 4; ++r) {                                               \
            const float iv = acc[0][r], fv = acc[1][r];                             \
            const float gv = acc[2][r], ov = acc[3][r];                             \
            const float si = sigmoid_f(iv);                                         \
            const float sf = sigmoid_f(fv);                                         \
            const float tg = tanh_f(gv);                                            \
            const float so = sigmoid_f(ov);                                         \
            const float cc = sf * cst[r] + si * tg;                                 \
            cst[r] = cc;                                                            \
            const float hv = so * tanh_f(cc);                                       \
            hlast[r] = hv;                                                          \
            *(short*)(wb + wboff0 + r * 16) = f2bf(hv);                             \
        }                                                                           \
        __syncthreads();                                                            \
    }

#pragma unroll 1
    for (int t2 = 0; t2 < T; t2 += 2) {
        HALF_STEP(0, t2,     xlo0, xhi0, xlo1, xhi1)
        HALF_STEP(1, t2 + 1, xlo1, xhi1, xlo0, xhi0)
    }
#undef HALF_STEP

    // ---- tail pred: t = T-1 uses h_{T-1}, sitting in buffer 0 ----
    if (w == 0) {
        f32x4 pacc = (f32x4){bo, bo, bo, bo};
#pragma unroll
        for (int kt = 0; kt < 4; ++kt) {
            s16x8 Af = *(const s16x8*)(smem + kt * 1024 + L * 16);
            pacc = MFMA_B16(Af, Bp[kt], pacc);
        }
        if (col == 0) {
#pragma unroll
            for (int r = 0; r < 4; ++r)
                out[((size_t)(bg * 16 + quad * 4 + r) * T + (T - 1)) * N + n] = pacc[r];
        }
    }

    // final hT, cT (fp32 from registers)
#pragma unroll
    for (int r = 0; r < 4; ++r) {
        const int bglob = bg * 16 + quad * 4 + r;
        const int j = w * 16 + col;
        out[HT_OFF + ((size_t)n * B + bglob) * H + j] = hlast[r];
        out[CT_OFF + ((size_t)n * B + bglob) * H + j] = cst[r];
    }
}

extern "C" void kernel_launch(void* const* d_in, const int* in_sizes, int n_in,
                              void* d_out, int out_size, void* d_ws, size_t ws_size,
                              hipStream_t stream) {
    const float* X     = (const float*)d_in[0];
    const float* W_ih  = (const float*)d_in[1];
    const float* W_hh  = (const float*)d_in[2];
    const float* b_ih  = (const float*)d_in[3];
    const float* b_hh  = (const float*)d_in[4];
    const float* W_out = (const float*)d_in[5];
    const float* b_out = (const float*)d_in[6];
    float* out = (float*)d_out;

    clstm_kernel<<<dim3(64), dim3(512), 0, stream>>>(
        X, W_ih, W_hh, b_ih, b_hh, W_out, b_out, out);
}

// Round 3
// 465.272 us; speedup vs baseline: 2.4551x; 2.2836x over previous
//
#include <hip/hip_runtime.h>
#include <hip/hip_bf16.h>

typedef __attribute__((ext_vector_type(8))) short s16x8;
typedef __attribute__((ext_vector_type(4))) float f32x4;

#define MFMA_B16(a, b, c) __builtin_amdgcn_mfma_f32_16x16x32_bf16((a), (b), (c), 0, 0, 0)

static __device__ __forceinline__ short f2bf(float f) {
    __hip_bfloat16 h = __float2bfloat16(f);
    return __builtin_bit_cast(short, h);
}
static __device__ __forceinline__ float sigmoid_f(float x) {
    return __fdividef(1.0f, 1.0f + exp2f(-1.4426950408889634f * x));
}
static __device__ __forceinline__ float tanh_f(float x) {
    return 1.0f - 2.0f * __fdividef(1.0f, 1.0f + exp2f(2.8853900817779268f * x));
}

// pre-pass: X fp32 -> bf16 in workspace (X is re-read every step by all WGs)
__global__ void xcvt_kernel(const float* __restrict__ X, short* __restrict__ Xb, int n) {
    int i = (blockIdx.x * 256 + threadIdx.x) * 4;
    if (i < n) {
        float4 v = *(const float4*)(X + i);
        short4 o;
        o.x = f2bf(v.x); o.y = f2bf(v.y); o.z = f2bf(v.z); o.w = f2bf(v.w);
        *(short4*)(Xb + i) = o;
    }
}

// Ensemble LSTM, batch-split-8: WG = (series n, batch-group of 4). 256 WGs = 256 CUs.
// 8 waves; wave w owns gate tiles {w, w+8, w+16, w+24} (i,f,g,o) for hidden cols w*16..+15.
// Batch b (0..3) mapped to MFMA row m=4b -> C rows land in reg 0 of each quad:
// epilogue = ONE cell/lane (10 trans ops vs 40) with all lanes active.
// pred head: extra MFMA tile (B col0 = W_out), rotated across waves (w == t&7),
// staged in LDS, flushed to global after the loop (no per-step vmcnt drain at barrier).
// LDS: [0,8K) double-buffered h A-frag (frag-linear), [8K,16K) pred stage [b][t] fp32.
template<bool BF16X>
__global__ __launch_bounds__(512, 2)
void clstm_kernel(const float* __restrict__ X,
                  const short* __restrict__ Xb,
                  const float* __restrict__ W_ih,
                  const float* __restrict__ W_hh,
                  const float* __restrict__ b_ih,
                  const float* __restrict__ b_hh,
                  const float* __restrict__ W_out,
                  const float* __restrict__ b_out,
                  float* __restrict__ out)
{
    constexpr int B = 32, T = 512, N = 32, H = 128, G = 512;  // G = 4H
    constexpr int HT_OFF = B * T * N;
    constexpr int CT_OFF = HT_OFF + N * B * H;
    constexpr int PRED_OFF = 8192;

    __shared__ __align__(16) unsigned char smem[16384];

    const int tid  = threadIdx.x;
    const int w    = tid >> 6;   // wave 0..7
    const int L    = tid & 63;
    const int col  = L & 15;
    const int quad = L >> 4;
    const int n    = blockIdx.x & 31;   // series (8 sharers of n land on one XCD)
    const int bgrp = blockIdx.x >> 5;   // batch group (4 batches)

    // ---- loop-invariant weight fragments (fp32 -> bf16, one time) ----
    // B-frag (16x16x32): lane holds gate col g = tile*16 + col, k = kt*32 + quad*8 + jj
    s16x8 Bh[4][4];  // [gate tt][kt]
    s16x8 Bx[4];     // [gate tt]  k = input p 0..31
    float bias4[4];
#pragma unroll
    for (int tt = 0; tt < 4; ++tt) {
        const int g = (w + 8 * tt) * 16 + col;
        const float* whr = W_hh + ((size_t)n * G + g) * H + quad * 8;
#pragma unroll
        for (int kt = 0; kt < 4; ++kt) {
            const float* p = whr + kt * 32;
#pragma unroll
            for (int jj = 0; jj < 8; ++jj) Bh[tt][kt][jj] = f2bf(p[jj]);
        }
        const float* wir = W_ih + ((size_t)n * G + g) * N + quad * 8;
#pragma unroll
        for (int jj = 0; jj < 8; ++jj) Bx[tt][jj] = f2bf(wir[jj]);
        bias4[tt] = b_ih[n * G + g] + b_hh[n * G + g];
    }

    // ---- pred tile (all waves; rotated use): B col 0 = W_out ----
    s16x8 Bp[4];
    const float bo = b_out[n];
#pragma unroll
    for (int kt = 0; kt < 4; ++kt) {
        const float* wp = W_out + n * H + kt * 32 + quad * 8;
#pragma unroll
        for (int jj = 0; jj < 8; ++jj)
            Bp[kt][jj] = (col == 0) ? f2bf(wp[jj]) : (short)0;
    }

    // ---- h writer offset: cell (batch=quad -> m=4*quad, j=w*16+col) ----
    int wboff;
    {
        const int j = w * 16 + col;
        wboff = (j >> 5) * 1024 + (((((j >> 3) & 3) << 4) | (quad << 2)) * 16) + (j & 7) * 2;
    }

    // ---- x loader: lanes with col%4==0 carry batch b=col>>2 at row m=col ----
    const bool xactive = (col & 3) == 0;
    const int  xb      = bgrp * 4 + (col >> 2);
    const float* xp = X  + ((size_t)xb * T) * N + quad * 8;
    const short* xbp = BF16X ? (Xb + ((size_t)xb * T) * N + quad * 8) : nullptr;

    // zero frag buffers (rows m%4!=0 must stay 0 forever) + pred stage
    *(float4*)(smem + tid * 16)        = make_float4(0.f, 0.f, 0.f, 0.f);
    *(float4*)(smem + 8192 + tid * 16) = make_float4(0.f, 0.f, 0.f, 0.f);

    float cst = 0.f, hlast = 0.f;

    auto loadx = [&](int t) -> s16x8 {
        s16x8 r = (s16x8)(short)0;
        if (xactive) {
            if constexpr (BF16X) {
                r = *(const s16x8*)(xbp + (size_t)t * N);
            } else {
                float4 lo = *(const float4*)(xp + (size_t)t * N);
                float4 hi = *(const float4*)(xp + (size_t)t * N + 4);
                r[0] = f2bf(lo.x); r[1] = f2bf(lo.y); r[2] = f2bf(lo.z); r[3] = f2bf(lo.w);
                r[4] = f2bf(hi.x); r[5] = f2bf(hi.y); r[6] = f2bf(hi.z); r[7] = f2bf(hi.w);
            }
        }
        return r;
    };

    s16x8 x0 = loadx(0), x1;

    __syncthreads();

#define HALF_STEP(P, TCUR, XC, XN)                                                  \
    {                                                                               \
        const unsigned char* rb = smem + (P) * 4096;                                \
        s16x8 Af[4];                                                                \
        _Pragma("unroll")                                                           \
        for (int kt = 0; kt < 4; ++kt)                                              \
            Af[kt] = *(const s16x8*)(rb + kt * 1024 + L * 16);                      \
        const int tnext = ((TCUR) + 1 < T) ? (TCUR) + 1 : T - 1;                    \
        XN = loadx(tnext);                                                          \
        f32x4 acc[4];                                                               \
        _Pragma("unroll")                                                           \
        for (int tt = 0; tt < 4; ++tt)                                              \
            acc[tt] = (f32x4){bias4[tt], bias4[tt], bias4[tt], bias4[tt]};          \
        _Pragma("unroll")                                                           \
        for (int kt = 0; kt < 4; ++kt) {                                            \
            _Pragma("unroll")                                                       \
            for (int tt = 0; tt < 4; ++tt)                                          \
                acc[tt] = MFMA_B16(Af[kt], Bh[tt][kt], acc[tt]);                    \
        }                                                                           \
        _Pragma("unroll")                                                           \
        for (int tt = 0; tt < 4; ++tt)                                              \
            acc[tt] = MFMA_B16(XC, Bx[tt], acc[tt]);                                \
        if ((TCUR) > 0 && w == ((TCUR) & 7)) {                                      \
            f32x4 pacc = (f32x4){bo, bo, bo, bo};                                   \
            _Pragma("unroll")                                                       \
            for (int kt = 0; kt < 4; ++kt)                                          \
                pacc = MFMA_B16(Af[kt], Bp[kt], pacc);                              \
            if (col == 0)                                                           \
                *(float*)(smem + PRED_OFF + ((quad << 9) + (TCUR) - 1) * 4) =       \
                    pacc[0];                                                        \
        }                                                                           \
        {                                                                           \
            const float iv = acc[0][0], fv = acc[1][0];                             \
            const float gv = acc[2][0], ov = acc[3][0];                             \
            const float cc = sigmoid_f(fv) * cst + sigmoid_f(iv) * tanh_f(gv);      \
            cst = cc;                                                               \
            const float hv = sigmoid_f(ov) * tanh_f(cc);                            \
            hlast = hv;                                                             \
            *(short*)(smem + ((P) ^ 1) * 4096 + wboff) = f2bf(hv);                  \
        }                                                                           \
        __syncthreads();                                                            \
    }

#pragma unroll 1
    for (int t2 = 0; t2 < T; t2 += 2) {
        HALF_STEP(0, t2,     x0, x1)
        HALF_STEP(1, t2 + 1, x1, x0)
    }
#undef HALF_STEP

    // ---- tail pred: t = T-1 uses h_{T-1}, sitting in buffer 0 ----
    if (w == 0) {
        f32x4 pacc = (f32x4){bo, bo, bo, bo};
#pragma unroll
        for (int kt = 0; kt < 4; ++kt) {
            s16x8 Af = *(const s16x8*)(smem + kt * 1024 + L * 16);
            pacc = MFMA_B16(Af, Bp[kt], pacc);
        }
        if (col == 0)
            *(float*)(smem + PRED_OFF + ((quad << 9) + (T - 1)) * 4) = pacc[0];
    }
    __syncthreads();

    // ---- flush pred stage -> global ----
#pragma unroll
    for (int e = tid; e < 4 * T; e += 512) {
        const int b = e >> 9, t = e & (T - 1);
        out[((size_t)(bgrp * 4 + b) * T + t) * N + n] =
            *(const float*)(smem + PRED_OFF + e * 4);
    }

    // ---- final hT, cT (fp32 from registers; lane owns cell (quad, w*16+col)) ----
    {
        const int bglob = bgrp * 4 + quad;
        const int j = w * 16 + col;
        out[HT_OFF + ((size_t)n * B + bglob) * H + j] = hlast;
        out[CT_OFF + ((size_t)n * B + bglob) * H + j] = cst;
    }
}

extern "C" void kernel_launch(void* const* d_in, const int* in_sizes, int n_in,
                              void* d_out, int out_size, void* d_ws, size_t ws_size,
                              hipStream_t stream) {
    const float* X     = (const float*)d_in[0];
    const float* W_ih  = (const float*)d_in[1];
    const float* W_hh  = (const float*)d_in[2];
    const float* b_ih  = (const float*)d_in[3];
    const float* b_hh  = (const float*)d_in[4];
    const float* W_out = (const float*)d_in[5];
    const float* b_out = (const float*)d_in[6];
    float* out = (float*)d_out;

    const int xelems = 32 * 512 * 32;  // B*T*N
    const bool usebf = ws_size >= (size_t)xelems * sizeof(short);

    if (usebf) {
        short* Xb = (short*)d_ws;
        xcvt_kernel<<<dim3(xelems / 1024), dim3(256), 0, stream>>>(X, Xb, xelems);
        clstm_kernel<true><<<dim3(256), dim3(512), 0, stream>>>(
            X, Xb, W_ih, W_hh, b_ih, b_hh, W_out, b_out, out);
    } else {
        clstm_kernel<false><<<dim3(256), dim3(512), 0, stream>>>(
            X, nullptr, W_ih, W_hh, b_ih, b_hh, W_out, b_out, out);
    }
}

// Round 4
// 366.012 us; speedup vs baseline: 3.1209x; 1.2712x over previous
//
#include <hip/hip_runtime.h>
#include <hip/hip_bf16.h>

typedef __attribute__((ext_vector_type(8))) short s16x8;
typedef __attribute__((ext_vector_type(4))) float f32x4;

#define MFMA_B16(a, b, c) __builtin_amdgcn_mfma_f32_16x16x32_bf16((a), (b), (c), 0, 0, 0)

static __device__ __forceinline__ short f2bf(float f) {
    __hip_bfloat16 h = __float2bfloat16(f);
    return __builtin_bit_cast(short, h);
}
static __device__ __forceinline__ float rcp_f(float x) {
    return __builtin_amdgcn_rcpf(x);
}

// pre-pass: X fp32 -> bf16 in workspace
__global__ void xcvt_kernel(const float* __restrict__ X, short* __restrict__ Xb, int n) {
    int i = (blockIdx.x * 256 + threadIdx.x) * 4;
    if (i < n) {
        float4 v = *(const float4*)(X + i);
        short4 o;
        o.x = f2bf(v.x); o.y = f2bf(v.y); o.z = f2bf(v.z); o.w = f2bf(v.w);
        *(short4*)(Xb + i) = o;
    }
}

// Ensemble LSTM, batch-split-8: WG = (series n, batch-group of 4). 256 WGs = 256 CUs.
// Chain-overlap version: the h_t-independent work (bias + x_{t+1}.W_ih partial gates)
// is issued in the epilogue window of step t; acc init movs eliminated by using a
// persistent bias f32x4 as the MFMA C operand. Activations use fused reciprocals
// (8 trans/cell instead of 10).
template<bool BF16X>
__global__ __launch_bounds__(512, 2)
void clstm_kernel(const float* __restrict__ X,
                  const short* __restrict__ Xb,
                  const float* __restrict__ W_ih,
                  const float* __restrict__ W_hh,
                  const float* __restrict__ b_ih,
                  const float* __restrict__ b_hh,
                  const float* __restrict__ W_out,
                  const float* __restrict__ b_out,
                  float* __restrict__ out)
{
    constexpr int B = 32, T = 512, N = 32, H = 128, G = 512;  // G = 4H
    constexpr int HT_OFF = B * T * N;
    constexpr int CT_OFF = HT_OFF + N * B * H;
    constexpr int PRED_OFF = 8192;
    constexpr float C1 = 1.4426950408889634f;   // log2(e)

    __shared__ __align__(16) unsigned char smem[16384];

    const int tid  = threadIdx.x;
    const int w    = tid >> 6;   // wave 0..7
    const int L    = tid & 63;
    const int col  = L & 15;
    const int quad = L >> 4;
    const int n    = blockIdx.x & 31;   // series
    const int bgrp = blockIdx.x >> 5;   // batch group (4 batches)

    // ---- loop-invariant weight fragments (fp32 -> bf16, once) ----
    s16x8 Bh[4][4];  // [gate tt][kt]
    s16x8 Bx[4];     // [gate tt]  k = input p 0..31
    f32x4 biasv[4];  // persistent MFMA C operand (bias broadcast)
#pragma unroll
    for (int tt = 0; tt < 4; ++tt) {
        const int g = (w + 8 * tt) * 16 + col;
        const float* whr = W_hh + ((size_t)n * G + g) * H + quad * 8;
#pragma unroll
        for (int kt = 0; kt < 4; ++kt) {
            const float* p = whr + kt * 32;
#pragma unroll
            for (int jj = 0; jj < 8; ++jj) Bh[tt][kt][jj] = f2bf(p[jj]);
        }
        const float* wir = W_ih + ((size_t)n * G + g) * N + quad * 8;
#pragma unroll
        for (int jj = 0; jj < 8; ++jj) Bx[tt][jj] = f2bf(wir[jj]);
        const float bb = b_ih[n * G + g] + b_hh[n * G + g];
        biasv[tt] = (f32x4){bb, bb, bb, bb};
    }

    // ---- pred tile: B col 0 = W_out, rotated across waves ----
    s16x8 Bp[4];
    const float bo = b_out[n];
    const f32x4 bov = (f32x4){bo, bo, bo, bo};
#pragma unroll
    for (int kt = 0; kt < 4; ++kt) {
        const float* wp = W_out + n * H + kt * 32 + quad * 8;
#pragma unroll
        for (int jj = 0; jj < 8; ++jj)
            Bp[kt][jj] = (col == 0) ? f2bf(wp[jj]) : (short)0;
    }

    // ---- h writer offset: cell (batch=quad -> m=4*quad, j=w*16+col) ----
    int wboff;
    {
        const int j = w * 16 + col;
        wboff = (j >> 5) * 1024 + (((((j >> 3) & 3) << 4) | (quad << 2)) * 16) + (j & 7) * 2;
    }

    // ---- x loader: lanes with col%4==0 carry batch b=col>>2 at row m=col ----
    const bool xactive = (col & 3) == 0;
    const int  xb      = bgrp * 4 + (col >> 2);
    const float* xp  = X + ((size_t)xb * T) * N + quad * 8;
    const short* xbp = BF16X ? (Xb + ((size_t)xb * T) * N + quad * 8) : nullptr;

    // zero frag buffers (pad rows must stay 0) + pred stage
    *(float4*)(smem + tid * 16)        = make_float4(0.f, 0.f, 0.f, 0.f);
    *(float4*)(smem + 8192 + tid * 16) = make_float4(0.f, 0.f, 0.f, 0.f);

    float cst = 0.f, hlast = 0.f;

    auto loadx = [&](int t) -> s16x8 {
        s16x8 r = (s16x8)(short)0;
        if (xactive) {
            if constexpr (BF16X) {
                r = *(const s16x8*)(xbp + (size_t)t * N);
            } else {
                float4 lo = *(const float4*)(xp + (size_t)t * N);
                float4 hi = *(const float4*)(xp + (size_t)t * N + 4);
                r[0] = f2bf(lo.x); r[1] = f2bf(lo.y); r[2] = f2bf(lo.z); r[3] = f2bf(lo.w);
                r[4] = f2bf(hi.x); r[5] = f2bf(hi.y); r[6] = f2bf(hi.z); r[7] = f2bf(hi.w);
            }
        }
        return r;
    };

    // prologue: partial gates for t=0 (bias + x_0.Wx), prefetch x_1, x_2
    s16x8 xA, xB;
    {
        s16x8 x0 = loadx(0);
        xA = loadx(1);
        xB = loadx(2);
        // accN computed below uses biasv as C: no init movs
        // (declared here, filled in prologue MFMAs)
    }
    f32x4 accN[4];
    {
        s16x8 x0 = loadx(0);
#pragma unroll
        for (int tt = 0; tt < 4; ++tt)
            accN[tt] = MFMA_B16(x0, Bx[tt], biasv[tt]);
    }

    __syncthreads();

#define STEP(P, TCUR)                                                               \
    {                                                                               \
        const unsigned char* rb = smem + (P) * 4096;                                \
        s16x8 Af[4];                                                                \
        _Pragma("unroll")                                                           \
        for (int kt = 0; kt < 4; ++kt)                                              \
            Af[kt] = *(const s16x8*)(rb + kt * 1024 + L * 16);                      \
        f32x4 acc[4];                                                               \
        _Pragma("unroll")                                                           \
        for (int tt = 0; tt < 4; ++tt) acc[tt] = accN[tt];                          \
        _Pragma("unroll")                                                           \
        for (int kt = 0; kt < 4; ++kt) {                                            \
            _Pragma("unroll")                                                       \
            for (int tt = 0; tt < 4; ++tt)                                          \
                acc[tt] = MFMA_B16(Af[kt], Bh[tt][kt], acc[tt]);                    \
        }                                                                           \
        if (w == ((TCUR) & 7)) {                                                    \
            f32x4 pacc = bov;                                                       \
            _Pragma("unroll")                                                       \
            for (int kt = 0; kt < 4; ++kt)                                          \
                pacc = MFMA_B16(Af[kt], Bp[kt], pacc);                              \
            if ((TCUR) > 0 && col == 0)                                             \
                *(float*)(smem + PRED_OFF + ((quad << 9) + (TCUR) - 1) * 4) =       \
                    pacc[0];                                                        \
        }                                                                           \
        /* overlap window: h_t-independent partial gates for t+1 */                 \
        _Pragma("unroll")                                                           \
        for (int tt = 0; tt < 4; ++tt)                                              \
            accN[tt] = MFMA_B16(xA, Bx[tt], biasv[tt]);                             \
        xA = xB;                                                                    \
        xB = loadx(((TCUR) + 3 < T) ? (TCUR) + 3 : T - 1);                          \
        /* epilogue: fused-rcp activations (8 trans) */                             \
        {                                                                           \
            const float iv = acc[0][0], fv = acc[1][0];                             \
            const float gv = acc[2][0], ov = acc[3][0];                             \
            const float ei = exp2f(-C1 * iv);                                       \
            const float ef = exp2f(-C1 * fv);                                       \
            const float eg = exp2f(-2.0f * C1 * gv);                                \
            const float eo = exp2f(-C1 * ov);                                       \
            const float sf = rcp_f(1.0f + ef);                                      \
            const float itg = (1.0f - eg) * rcp_f((1.0f + ei) * (1.0f + eg));       \
            const float cc = __builtin_fmaf(sf, cst, itg);                          \
            cst = cc;                                                               \
            const float ec = exp2f(-2.0f * C1 * cc);                                \
            const float hv = (1.0f - ec) * rcp_f((1.0f + eo) * (1.0f + ec));        \
            hlast = hv;                                                             \
            *(short*)(smem + ((P) ^ 1) * 4096 + wboff) = f2bf(hv);                  \
        }                                                                           \
        __syncthreads();                                                            \
    }

#pragma unroll 1
    for (int t2 = 0; t2 < T; t2 += 2) {
        STEP(0, t2)
        STEP(1, t2 + 1)
    }
#undef STEP

    // ---- tail pred: t = T-1 uses h_{T-1}, sitting in buffer 0 ----
    if (w == 0) {
        f32x4 pacc = bov;
#pragma unroll
        for (int kt = 0; kt < 4; ++kt) {
            s16x8 Af = *(const s16x8*)(smem + kt * 1024 + L * 16);
            pacc = MFMA_B16(Af, Bp[kt], pacc);
        }
        if (col == 0)
            *(float*)(smem + PRED_OFF + ((quad << 9) + (T - 1)) * 4) = pacc[0];
    }
    __syncthreads();

    // ---- flush pred stage -> global ----
#pragma unroll
    for (int e = tid; e < 4 * T; e += 512) {
        const int b = e >> 9, t = e & (T - 1);
        out[((size_t)(bgrp * 4 + b) * T + t) * N + n] =
            *(const float*)(smem + PRED_OFF + e * 4);
    }

    // ---- final hT, cT ----
    {
        const int bglob = bgrp * 4 + quad;
        const int j = w * 16 + col;
        out[HT_OFF + ((size_t)n * B + bglob) * H + j] = hlast;
        out[CT_OFF + ((size_t)n * B + bglob) * H + j] = cst;
    }
}

extern "C" void kernel_launch(void* const* d_in, const int* in_sizes, int n_in,
                              void* d_out, int out_size, void* d_ws, size_t ws_size,
                              hipStream_t stream) {
    const float* X     = (const float*)d_in[0];
    const float* W_ih  = (const float*)d_in[1];
    const float* W_hh  = (const float*)d_in[2];
    const float* b_ih  = (const float*)d_in[3];
    const float* b_hh  = (const float*)d_in[4];
    const float* W_out = (const float*)d_in[5];
    const float* b_out = (const float*)d_in[6];
    float* out = (float*)d_out;

    const int xelems = 32 * 512 * 32;  // B*T*N
    const bool usebf = ws_size >= (size_t)xelems * sizeof(short);

    if (usebf) {
        short* Xb = (short*)d_ws;
        xcvt_kernel<<<dim3(xelems / 1024), dim3(256), 0, stream>>>(X, Xb, xelems);
        clstm_kernel<true><<<dim3(256), dim3(512), 0, stream>>>(
            X, Xb, W_ih, W_hh, b_ih, b_hh, W_out, b_out, out);
    } else {
        clstm_kernel<false><<<dim3(256), dim3(512), 0, stream>>>(
            X, nullptr, W_ih, W_hh, b_ih, b_hh, W_out, b_out, out);
    }
}